// Round 1
// baseline (31.880 us; speedup 1.0000x reference)
//
#include <hip/hip_runtime.h>

// RangeLoss: out = sum_i[(p-t_adj)^2 + (log p - log t_adj)^2] / N^2
// t_adj = p if (p*1.05 > t && p*0.95 < t) else t.  N = 2^24 -> scale = 2^-48.

constexpr int RL_THREADS = 256;
constexpr int RL_BLOCKS  = 2048;   // 256 CU * 8 blocks/CU; grid-stride the rest

__global__ __launch_bounds__(RL_THREADS) void rangeloss_partial(
    const float* __restrict__ preds, const float* __restrict__ target,
    float* __restrict__ partials, int n) {
  const int tid    = blockIdx.x * RL_THREADS + threadIdx.x;
  const int stride = RL_BLOCKS * RL_THREADS;
  const int n4     = n >> 2;
  const float4* __restrict__ p4 = reinterpret_cast<const float4*>(preds);
  const float4* __restrict__ t4 = reinterpret_cast<const float4*>(target);

  float acc = 0.0f;
  for (int i = tid; i < n4; i += stride) {
    float4 p = p4[i];
    float4 t = t4[i];
    #pragma unroll
    for (int j = 0; j < 4; ++j) {
      float pj = (&p.x)[j];
      float tj = (&t.x)[j];
      bool in_range = (pj * 1.05f > tj) && (pj * 0.95f < tj);
      float ta = in_range ? pj : tj;
      float d  = pj - ta;                       // 0 when in_range
      float ld = __logf(pj) - __logf(ta);       // 0 when in_range
      acc += d * d + ld * ld;
    }
  }

  // wave(64) shuffle reduce
  #pragma unroll
  for (int off = 32; off > 0; off >>= 1) acc += __shfl_down(acc, off, 64);

  __shared__ float smem[RL_THREADS / 64];
  const int lane = threadIdx.x & 63;
  const int wid  = threadIdx.x >> 6;
  if (lane == 0) smem[wid] = acc;
  __syncthreads();
  if (threadIdx.x == 0) {
    float s = 0.0f;
    #pragma unroll
    for (int w = 0; w < RL_THREADS / 64; ++w) s += smem[w];
    partials[blockIdx.x] = s;
  }
}

__global__ __launch_bounds__(RL_THREADS) void rangeloss_final(
    const float* __restrict__ partials, float* __restrict__ out, float scale) {
  float acc = 0.0f;
  for (int i = threadIdx.x; i < RL_BLOCKS; i += RL_THREADS) acc += partials[i];
  #pragma unroll
  for (int off = 32; off > 0; off >>= 1) acc += __shfl_down(acc, off, 64);

  __shared__ float smem[RL_THREADS / 64];
  const int lane = threadIdx.x & 63;
  const int wid  = threadIdx.x >> 6;
  if (lane == 0) smem[wid] = acc;
  __syncthreads();
  if (threadIdx.x == 0) {
    float s = 0.0f;
    #pragma unroll
    for (int w = 0; w < RL_THREADS / 64; ++w) s += smem[w];
    out[0] = s * scale;
  }
}

extern "C" void kernel_launch(void* const* d_in, const int* in_sizes, int n_in,
                              void* d_out, int out_size, void* d_ws, size_t ws_size,
                              hipStream_t stream) {
  const float* preds  = (const float*)d_in[0];
  const float* target = (const float*)d_in[1];
  float* out      = (float*)d_out;
  float* partials = (float*)d_ws;          // RL_BLOCKS floats = 8 KiB
  const int n = in_sizes[0];

  // loss = sum / (n * n); n = 2^24 -> exact 2^-48
  const float scale = (float)(1.0 / ((double)n * (double)n));

  rangeloss_partial<<<RL_BLOCKS, RL_THREADS, 0, stream>>>(preds, target, partials, n);
  rangeloss_final<<<1, RL_THREADS, 0, stream>>>(partials, out, scale);
}

// Round 2
// 31.789 us; speedup vs baseline: 1.0029x; 1.0029x over previous
//
#include <hip/hip_runtime.h>

// RangeLoss: out = sum_i[(p-t_adj)^2 + (log p - log t_adj)^2] / N^2
// t_adj = p if (p*1.05 > t && p*0.95 < t) else t.  N = 2^24 -> scale = 2^-48.
//
// R1: latency-bound (L3-resident replay still ~42us, VALUBusy 30%, HBM 20%).
// Fix: unroll x4 -> 8 independent float4 loads (128B/lane) in flight per
// iteration before compute, so vmcnt staging hides L3/HBM latency.

constexpr int RL_THREADS = 256;
constexpr int RL_BLOCKS  = 2048;   // 256 CU * 8 blocks/CU
constexpr int RL_UNROLL  = 4;      // float4s per thread per outer iteration

__global__ __launch_bounds__(RL_THREADS) void rangeloss_partial(
    const float* __restrict__ preds, const float* __restrict__ target,
    float* __restrict__ partials, int n) {
  const int tid    = blockIdx.x * RL_THREADS + threadIdx.x;
  const int stride = RL_BLOCKS * RL_THREADS;          // in float4 units
  const int n4     = n >> 2;
  const float4* __restrict__ p4 = reinterpret_cast<const float4*>(preds);
  const float4* __restrict__ t4 = reinterpret_cast<const float4*>(target);

  float acc = 0.0f;

  // Main loop: RL_UNROLL independent float4 pairs in flight before compute.
  int base = tid;
  for (; base + (RL_UNROLL - 1) * stride < n4; base += RL_UNROLL * stride) {
    float4 p[RL_UNROLL], t[RL_UNROLL];
    #pragma unroll
    for (int u = 0; u < RL_UNROLL; ++u) p[u] = p4[base + u * stride];
    #pragma unroll
    for (int u = 0; u < RL_UNROLL; ++u) t[u] = t4[base + u * stride];

    #pragma unroll
    for (int u = 0; u < RL_UNROLL; ++u) {
      #pragma unroll
      for (int j = 0; j < 4; ++j) {
        float pj = (&p[u].x)[j];
        float tj = (&t[u].x)[j];
        bool in_range = (pj * 1.05f > tj) && (pj * 0.95f < tj);
        float ta = in_range ? pj : tj;
        float d  = pj - ta;                     // 0 when in_range
        float ld = __logf(pj) - __logf(ta);     // 0 when in_range
        acc += d * d + ld * ld;
      }
    }
  }
  // Tail (empty for N=2^24 with these constants, kept for generality).
  for (; base < n4; base += stride) {
    float4 p = p4[base];
    float4 t = t4[base];
    #pragma unroll
    for (int j = 0; j < 4; ++j) {
      float pj = (&p.x)[j];
      float tj = (&t.x)[j];
      bool in_range = (pj * 1.05f > tj) && (pj * 0.95f < tj);
      float ta = in_range ? pj : tj;
      float d  = pj - ta;
      float ld = __logf(pj) - __logf(ta);
      acc += d * d + ld * ld;
    }
  }

  // wave(64) shuffle reduce
  #pragma unroll
  for (int off = 32; off > 0; off >>= 1) acc += __shfl_down(acc, off, 64);

  __shared__ float smem[RL_THREADS / 64];
  const int lane = threadIdx.x & 63;
  const int wid  = threadIdx.x >> 6;
  if (lane == 0) smem[wid] = acc;
  __syncthreads();
  if (threadIdx.x == 0) {
    float s = 0.0f;
    #pragma unroll
    for (int w = 0; w < RL_THREADS / 64; ++w) s += smem[w];
    partials[blockIdx.x] = s;
  }
}

__global__ __launch_bounds__(RL_THREADS) void rangeloss_final(
    const float* __restrict__ partials, float* __restrict__ out, float scale) {
  float acc = 0.0f;
  for (int i = threadIdx.x; i < RL_BLOCKS; i += RL_THREADS) acc += partials[i];
  #pragma unroll
  for (int off = 32; off > 0; off >>= 1) acc += __shfl_down(acc, off, 64);

  __shared__ float smem[RL_THREADS / 64];
  const int lane = threadIdx.x & 63;
  const int wid  = threadIdx.x >> 6;
  if (lane == 0) smem[wid] = acc;
  __syncthreads();
  if (threadIdx.x == 0) {
    float s = 0.0f;
    #pragma unroll
    for (int w = 0; w < RL_THREADS / 64; ++w) s += smem[w];
    out[0] = s * scale;
  }
}

extern "C" void kernel_launch(void* const* d_in, const int* in_sizes, int n_in,
                              void* d_out, int out_size, void* d_ws, size_t ws_size,
                              hipStream_t stream) {
  const float* preds  = (const float*)d_in[0];
  const float* target = (const float*)d_in[1];
  float* out      = (float*)d_out;
  float* partials = (float*)d_ws;          // RL_BLOCKS floats = 8 KiB
  const int n = in_sizes[0];

  // loss = sum / (n * n); n = 2^24 -> exact 2^-48
  const float scale = (float)(1.0 / ((double)n * (double)n));

  rangeloss_partial<<<RL_BLOCKS, RL_THREADS, 0, stream>>>(preds, target, partials, n);
  rangeloss_final<<<1, RL_THREADS, 0, stream>>>(partials, out, scale);
}